// Round 9
// baseline (87.034 us; speedup 1.0000x reference)
//
#include <hip/hip_runtime.h>
#include <hip/hip_bf16.h>

#define B_   4096
#define S_   32
#define IN_  256
#define H_   128
#define OUT_ 256
#define BM_  64    // rows per block (one tile per block, R1 tiling)

typedef __attribute__((ext_vector_type(8))) short bf16x8;
typedef __attribute__((ext_vector_type(4))) float f32x4;
typedef unsigned long long ull;

__device__ __forceinline__ unsigned short f2bf(float f) {
    union { float f; unsigned u; } v; v.f = f;
    unsigned r = v.u + 0x7FFFu + ((v.u >> 16) & 1u);   // round-to-nearest-even
    return (unsigned short)(r >> 16);
}

__device__ __forceinline__ unsigned cvt_pk(float lo, float hi) {
    unsigned r;
    asm("v_cvt_pk_bf16_f32 %0, %1, %2" : "=v"(r) : "v"(lo), "v"(hi));
    return r;
}

// Transpose + f32->bf16 convert for BOTH weight tensors in one launch.
// blocks [0,1024): W1 [S][256][128] -> w1t [S][128][256]
// blocks [1024,2048): W2 [S][128][256] -> w2t [S][256][128]
__global__ void transpose_cvt_both(const float* __restrict__ W1,
                                   const float* __restrict__ W2,
                                   unsigned short* __restrict__ w1t,
                                   unsigned short* __restrict__ w2t) {
    __shared__ float tile[32][33];
    int bid = blockIdx.x;
    const float* in; unsigned short* out; int R, C, rel;
    if (bid < 1024) { in = W1; out = w1t; R = IN_; C = H_;  rel = bid; }
    else            { in = W2; out = w2t; R = H_; C = OUT_; rel = bid - 1024; }
    const int tilesR = R >> 5, tilesC = C >> 5;
    const int s   = rel / (tilesR * tilesC);
    const int rem = rel % (tilesR * tilesC);
    const int tr  = rem / tilesC, tc = rem % tilesC;
    const float* ip = in + (size_t)s * R * C;
    unsigned short* op = out + (size_t)s * C * R;
    const int t  = threadIdx.x;
    const int c  = t & 31;
    const int r4 = t >> 5;
#pragma unroll
    for (int i = 0; i < 4; ++i) {
        int r = r4 * 4 + i;
        tile[r][c] = ip[(size_t)(tr * 32 + r) * C + tc * 32 + c];
    }
    __syncthreads();
#pragma unroll
    for (int i = 0; i < 4; ++i) {
        int orow = r4 * 4 + i;
        int ocol = c;
        op[(size_t)(tc * 32 + orow) * R + tr * 32 + ocol] = f2bf(tile[ocol][orow]);
    }
}

// Fused per-subband MLP. R8 structure (BM=64, grid 2048, 4 waves, prestreamed
// weights) + ASM-PINNED x staging: 16 global_load_dwordx4 issued via inline asm
// (compiler cannot sink or early-drain them), one vmcnt(0) with all 16 dest
// registers tied "+v" (no use can be hoisted above the wait), sched_barrier.
__global__ __launch_bounds__(256, 3) void subband_fused_kernel(
        const float* __restrict__ x,
        const unsigned short* __restrict__ w1t,   // [S][H][IN] bf16
        const float* __restrict__ b1,             // [S][H]
        const unsigned short* __restrict__ w2t,   // [S][OUT][H] bf16
        const float* __restrict__ b2,             // [S][OUT]
        float* __restrict__ out) {
    // LDS: [0,32768) xs = [64 rows][512 B] bf16 swizzled; [32768,49152) hs = [64][256 B].
    __shared__ __align__(16) unsigned char lds[49152];
    unsigned char* xs = lds;
    unsigned char* hs = lds + 32768;

    // Bijective XCD swizzle (2048 % 8 == 0): XCD c gets bids [256c,256c+256)
    // = subbands [4c,4c+4) -> 512 KB bf16 weights per XCD L2.
    const int raw = blockIdx.x;
    const int bid = (raw & 7) * 256 + (raw >> 3);
    const int s   = bid >> 6;            // 64 blocks per subband
    const int b0  = (bid & 63) << 6;     // first row of this 64-row tile

    const int tid  = threadIdx.x;
    const int lane = tid & 63;
    const int w    = tid >> 6;           // wave 0..3
    const int l15  = lane & 15;
    const int l4   = lane >> 4;          // 0..3

    const int c4 = tid & 63;             // float4 column index (staging)
    const int rb = tid >> 6;             // staging row offset 0..3

    const unsigned short* w1s = w1t + (size_t)s * H_ * IN_;
    const unsigned short* w2s = w2t + (size_t)s * OUT_ * H_;

    // ---- issue ALL x staging loads via asm (pinned: 16 in flight, 64 VGPRs) ----
    f32x4 v[16];
#pragma unroll
    for (int it = 0; it < 16; ++it) {
        const int r = it * 4 + rb;
        const float* ap = x + ((size_t)(b0 + r) * S_ + s) * IN_ + (c4 << 2);
        asm volatile("global_load_dwordx4 %0, %1, off" : "=v"(v[it]) : "v"(ap));
    }

    // ---- prestream ALL layer-1 weight fragments (L2 latency hides under x HBM) ----
    bf16x8 bb1[8][2];
#pragma unroll
    for (int kk = 0; kk < 8; ++kk)
#pragma unroll
        for (int ct = 0; ct < 2; ++ct)
            bb1[kk][ct] = *(const bf16x8*)(w1s
                + (size_t)((w << 5) + ct * 16 + l15) * IN_ + kk * 32 + l4 * 8);

    float bias1[2];
    bias1[0] = b1[s * H_ + (w << 5) + l15];
    bias1[1] = b1[s * H_ + (w << 5) + 16 + l15];
    float bias2[4];
#pragma unroll
    for (int ct = 0; ct < 4; ++ct)
        bias2[ct] = b2[s * OUT_ + (w << 6) + ct * 16 + l15];

    // ---- drain x loads; "+v" ties force every use below this point ----
    asm volatile("s_waitcnt vmcnt(0)"
                 : "+v"(v[0]), "+v"(v[1]), "+v"(v[2]), "+v"(v[3]),
                   "+v"(v[4]), "+v"(v[5]), "+v"(v[6]), "+v"(v[7]),
                   "+v"(v[8]), "+v"(v[9]), "+v"(v[10]), "+v"(v[11]),
                   "+v"(v[12]), "+v"(v[13]), "+v"(v[14]), "+v"(v[15]));
    __builtin_amdgcn_sched_barrier(0);

    // ---- convert staged x -> xs (bf16, XOR-swizzled) ----
#pragma unroll
    for (int it = 0; it < 16; ++it) {
        const int r = it * 4 + rb;
        ull p = (ull)cvt_pk(v[it][0], v[it][1]) | ((ull)cvt_pk(v[it][2], v[it][3]) << 32);
        *(ull*)(xs + r * 512 + ((c4 << 3) ^ ((r & 7) << 4))) = p;
    }
    __syncthreads();                       // barrier A: xs ready

    // ---- layer 1: H[64][128] = relu(X @ W1 + b1), wave w cols [32w,32w+32) ----
    f32x4 acc1[4][2];
#pragma unroll
    for (int rt = 0; rt < 4; ++rt)
#pragma unroll
        for (int ct = 0; ct < 2; ++ct)
#pragma unroll
            for (int i = 0; i < 4; ++i) acc1[rt][ct][i] = bias1[ct];
#pragma unroll
    for (int kk = 0; kk < 8; ++kk) {
        const int kb = kk * 32 + l4 * 8;
        bf16x8 a[4];
#pragma unroll
        for (int rt = 0; rt < 4; ++rt) {
            const int r = rt * 16 + l15;
            a[rt] = *(const bf16x8*)(xs + r * 512 + ((kb * 2) ^ ((r & 7) << 4)));
        }
#pragma unroll
        for (int rt = 0; rt < 4; ++rt)
#pragma unroll
            for (int ct = 0; ct < 2; ++ct)
                acc1[rt][ct] = __builtin_amdgcn_mfma_f32_16x16x32_bf16(
                    a[rt], bb1[kk][ct], acc1[rt][ct], 0, 0, 0);
    }

    // ---- prestream layer-2 weights, first half (oq=0: cols [64w,64w+32)) ----
    bf16x8 bb2a[4][2];
#pragma unroll
    for (int kk = 0; kk < 4; ++kk)
#pragma unroll
        for (int ct = 0; ct < 2; ++ct)
            bb2a[kk][ct] = *(const bf16x8*)(w2s
                + (size_t)((w << 6) + ct * 16 + l15) * H_ + kk * 32 + l4 * 8);

    // ---- relu -> hs (bf16, swizzled). C/D: col = l15 (n), row = l4*4+i (m) ----
#pragma unroll
    for (int rt = 0; rt < 4; ++rt)
#pragma unroll
        for (int ct = 0; ct < 2; ++ct)
#pragma unroll
            for (int i = 0; i < 4; ++i) {
                float hv = fmaxf(acc1[rt][ct][i], 0.0f);
                const int r = rt * 16 + l4 * 4 + i;
                const int n = (w << 5) + ct * 16 + l15;
                *(unsigned short*)(hs + r * 256 + ((n * 2) ^ ((r & 7) << 4))) = f2bf(hv);
            }
    __syncthreads();                       // barrier B: hs ready

    // ---- prestream layer-2 weights, second half (oq=1), hides under oq0 MFMA ----
    bf16x8 bb2b[4][2];
#pragma unroll
    for (int kk = 0; kk < 4; ++kk)
#pragma unroll
        for (int ct = 0; ct < 2; ++ct)
            bb2b[kk][ct] = *(const bf16x8*)(w2s
                + (size_t)((w << 6) + 32 + ct * 16 + l15) * H_ + kk * 32 + l4 * 8);

    // ---- layer 2, oq = 0: cols [64w, 64w+32) ----
    {
        f32x4 acc2[4][2];
#pragma unroll
        for (int rt = 0; rt < 4; ++rt)
#pragma unroll
            for (int ct = 0; ct < 2; ++ct)
#pragma unroll
                for (int i = 0; i < 4; ++i) acc2[rt][ct][i] = bias2[ct];
#pragma unroll
        for (int kk = 0; kk < 4; ++kk) {
            const int kb = kk * 32 + l4 * 8;
            bf16x8 a[4];
#pragma unroll
            for (int rt = 0; rt < 4; ++rt) {
                const int r = rt * 16 + l15;
                a[rt] = *(const bf16x8*)(hs + r * 256 + ((kb * 2) ^ ((r & 7) << 4)));
            }
#pragma unroll
            for (int rt = 0; rt < 4; ++rt)
#pragma unroll
                for (int ct = 0; ct < 2; ++ct)
                    acc2[rt][ct] = __builtin_amdgcn_mfma_f32_16x16x32_bf16(
                        a[rt], bb2a[kk][ct], acc2[rt][ct], 0, 0, 0);
        }
#pragma unroll
        for (int rt = 0; rt < 4; ++rt)
#pragma unroll
            for (int ct = 0; ct < 2; ++ct)
#pragma unroll
                for (int i = 0; i < 4; ++i) {
                    const int r = b0 + rt * 16 + l4 * 4 + i;
                    const int n = (w << 6) + ct * 16 + l15;
                    out[((size_t)r * S_ + s) * OUT_ + n] = acc2[rt][ct][i];
                }
    }
    // ---- layer 2, oq = 1: cols [64w+32, 64w+64) ----
    {
        f32x4 acc2[4][2];
#pragma unroll
        for (int rt = 0; rt < 4; ++rt)
#pragma unroll
            for (int ct = 0; ct < 2; ++ct)
#pragma unroll
                for (int i = 0; i < 4; ++i) acc2[rt][ct][i] = bias2[2 + ct];
#pragma unroll
        for (int kk = 0; kk < 4; ++kk) {
            const int kb = kk * 32 + l4 * 8;
            bf16x8 a[4];
#pragma unroll
            for (int rt = 0; rt < 4; ++rt) {
                const int r = rt * 16 + l15;
                a[rt] = *(const bf16x8*)(hs + r * 256 + ((kb * 2) ^ ((r & 7) << 4)));
            }
#pragma unroll
            for (int rt = 0; rt < 4; ++rt)
#pragma unroll
                for (int ct = 0; ct < 2; ++ct)
                    acc2[rt][ct] = __builtin_amdgcn_mfma_f32_16x16x32_bf16(
                        a[rt], bb2b[kk][ct], acc2[rt][ct], 0, 0, 0);
        }
#pragma unroll
        for (int rt = 0; rt < 4; ++rt)
#pragma unroll
            for (int ct = 0; ct < 2; ++ct)
#pragma unroll
                for (int i = 0; i < 4; ++i) {
                    const int r = b0 + rt * 16 + l4 * 4 + i;
                    const int n = (w << 6) + 32 + ct * 16 + l15;
                    out[((size_t)r * S_ + s) * OUT_ + n] = acc2[rt][ct][i];
                }
    }
}

extern "C" void kernel_launch(void* const* d_in, const int* in_sizes, int n_in,
                              void* d_out, int out_size, void* d_ws, size_t ws_size,
                              hipStream_t stream) {
    const float* x  = (const float*)d_in[0];
    const float* W1 = (const float*)d_in[1];
    const float* b1 = (const float*)d_in[2];
    const float* W2 = (const float*)d_in[3];
    const float* b2 = (const float*)d_in[4];
    float* out = (float*)d_out;

    unsigned short* w1t = (unsigned short*)d_ws;                 // [S][H][IN]  bf16: 2 MiB
    unsigned short* w2t = w1t + (size_t)S_ * H_ * IN_;           // [S][OUT][H] bf16: 2 MiB

    transpose_cvt_both<<<2048, 256, 0, stream>>>(W1, W2, w1t, w2t);
    subband_fused_kernel<<<S_ * (B_ / BM_), 256, 0, stream>>>(x, w1t, b1, w2t, b2, out);
}

// Round 10
// 81.254 us; speedup vs baseline: 1.0711x; 1.0711x over previous
//
#include <hip/hip_runtime.h>
#include <hip/hip_bf16.h>

#define B_   4096
#define S_   32
#define IN_  256
#define H_   128
#define OUT_ 256

typedef __attribute__((ext_vector_type(8))) short bf16x8;
typedef __attribute__((ext_vector_type(4))) float f32x4;
typedef unsigned long long ull;

__device__ __forceinline__ unsigned short f2bf(float f) {
    union { float f; unsigned u; } v; v.f = f;
    unsigned r = v.u + 0x7FFFu + ((v.u >> 16) & 1u);   // round-to-nearest-even
    return (unsigned short)(r >> 16);
}

__device__ __forceinline__ unsigned cvt_pk(float lo, float hi) {
    unsigned r;
    asm("v_cvt_pk_bf16_f32 %0, %1, %2" : "=v"(r) : "v"(lo), "v"(hi));
    return r;
}

// Transpose + f32->bf16 convert for BOTH weight tensors in one launch.
// blocks [0,1024): W1 [S][256][128] -> w1t [S][128][256]
// blocks [1024,2048): W2 [S][128][256] -> w2t [S][256][128]
__global__ void transpose_cvt_both(const float* __restrict__ W1,
                                   const float* __restrict__ W2,
                                   unsigned short* __restrict__ w1t,
                                   unsigned short* __restrict__ w2t) {
    __shared__ float tile[32][33];
    int bid = blockIdx.x;
    const float* in; unsigned short* out; int R, C, rel;
    if (bid < 1024) { in = W1; out = w1t; R = IN_; C = H_;  rel = bid; }
    else            { in = W2; out = w2t; R = H_; C = OUT_; rel = bid - 1024; }
    const int tilesR = R >> 5, tilesC = C >> 5;
    const int s   = rel / (tilesR * tilesC);
    const int rem = rel % (tilesR * tilesC);
    const int tr  = rem / tilesC, tc = rem % tilesC;
    const float* ip = in + (size_t)s * R * C;
    unsigned short* op = out + (size_t)s * C * R;
    const int t  = threadIdx.x;
    const int c  = t & 31;
    const int r4 = t >> 5;
#pragma unroll
    for (int i = 0; i < 4; ++i) {
        int r = r4 * 4 + i;
        tile[r][c] = ip[(size_t)(tr * 32 + r) * C + tc * 32 + c];
    }
    __syncthreads();
#pragma unroll
    for (int i = 0; i < 4; ++i) {
        int orow = r4 * 4 + i;
        int ocol = c;
        op[(size_t)(tc * 32 + orow) * R + tr * 32 + ocol] = f2bf(tile[ocol][orow]);
    }
}

// Weights-stationary fused MLP.
// grid = 256 blocks (1/CU), block = 512 thr (8 waves). ONE barrier total.
// Block: stage W1[s] (64KB) + W2[s] (64KB) into XOR-swizzled LDS once; then
// each wave autonomously streams 4 x-tiles of 16 rows:
//   x -> regs (asm dwordx4, next tile prefetched under current compute)
//   L1 swapped: mfma(A=W1 from LDS, B=x regs) -> D[h][m]
//   per-wave LDS repack (4KB slice, swizzled) -> A-frags for L2
//   L2 standard: mfma(A=h, B=W2 from LDS) -> out stores
__global__ __launch_bounds__(512, 2) void subband_fused_kernel(
        const float* __restrict__ x,
        const unsigned short* __restrict__ w1t,   // [S][H][IN] bf16
        const float* __restrict__ b1,             // [S][H]
        const unsigned short* __restrict__ w2t,   // [S][OUT][H] bf16
        const float* __restrict__ b2,             // [S][OUT]
        float* __restrict__ out) {
    // LDS: [0,64K) W1 swz [128 rows][512B]; [64K,128K) W2 swz [256 rows][256B];
    //      [128K,160K) per-wave repack slices 8 x 4KB.
    __shared__ __align__(16) unsigned char lds[163840];
    unsigned char* w1l = lds;
    unsigned char* w2l = lds + 65536;

    const int bid   = blockIdx.x;        // 0..255
    const int s     = bid & 31;          // subband
    const int chunk = bid >> 5;          // 0..7 -> rows [chunk*512, +512)
    const int tid   = threadIdx.x;       // 0..511
    const int w     = tid >> 6;          // wave 0..7
    const int lane  = tid & 63;
    const int l15   = lane & 15;
    const int l4    = lane >> 4;         // 0..3
    unsigned char* hsl = lds + 131072 + w * 4096;   // [16 m][256B] swz, private

    const unsigned short* w1s = w1t + (size_t)s * H_ * IN_;
    const unsigned short* w2s = w2t + (size_t)s * OUT_ * H_;
    const int rw = chunk * 512 + w * 64;            // wave's first row

    // ---- issue tile-0 x loads (16 dwordx4/lane, B-fragment addressing) ----
    f32x4 v[16];
    {
        const float* xr = x + ((size_t)(rw + l15) * S_ + s) * IN_ + l4 * 8;
#pragma unroll
        for (int kk = 0; kk < 8; ++kk) {
            asm volatile("global_load_dwordx4 %0, %1, off" : "=v"(v[2*kk])   : "v"(xr + kk*32));
            asm volatile("global_load_dwordx4 %0, %1, off" : "=v"(v[2*kk+1]) : "v"(xr + kk*32 + 4));
        }
    }

    // ---- stage W1 into LDS, swizzled (pre-swizzled global source) ----
    // target: w1l[h*512 + (colbyte ^ ((h&7)<<4))] = W1[h][colbyte/2]
#pragma unroll
    for (int n = 0; n < 8; ++n) {
        const int h  = n * 16 + (tid >> 5);
        const int cb = (tid & 31) * 16;
        const bf16x8 val = *(const bf16x8*)((const unsigned char*)w1s
                                            + h * 512 + (cb ^ ((h & 7) << 4)));
        *(bf16x8*)(w1l + n * 8192 + tid * 16) = val;
    }
    // ---- stage W2 likewise: w2l[o*256 + (cb ^ ((o&7)<<4))] = W2t[o][cb/2] ----
#pragma unroll
    for (int n = 0; n < 8; ++n) {
        const int o  = n * 32 + (tid >> 4);
        const int cb = (tid & 15) * 16;
        const bf16x8 val = *(const bf16x8*)((const unsigned char*)w2s
                                            + o * 256 + (cb ^ ((o & 7) << 4)));
        *(bf16x8*)(w2l + n * 8192 + tid * 16) = val;
    }

    // ---- hoist biases to registers (drained by the barrier below) ----
    float4 b1v[8];
#pragma unroll
    for (int hf = 0; hf < 8; ++hf)
        b1v[hf] = *(const float4*)(b1 + s * H_ + hf * 16 + l4 * 4);
    float b2v[16];
#pragma unroll
    for (int j = 0; j < 16; ++j)
        b2v[j] = b2[s * OUT_ + (j >> 3) * 128 + (j & 7) * 16 + l15];

    __syncthreads();                     // the ONLY barrier

    // ---- per-wave autonomous tile loop ----
#pragma unroll 1
    for (int t = 0; t < 4; ++t) {
        const int r0 = rw + t * 16;

        // (a) drain this tile's x loads (+ prev tile's stores)
        asm volatile("s_waitcnt vmcnt(0)"
                     : "+v"(v[0]), "+v"(v[1]), "+v"(v[2]), "+v"(v[3]),
                       "+v"(v[4]), "+v"(v[5]), "+v"(v[6]), "+v"(v[7]),
                       "+v"(v[8]), "+v"(v[9]), "+v"(v[10]), "+v"(v[11]),
                       "+v"(v[12]), "+v"(v[13]), "+v"(v[14]), "+v"(v[15])
                     :: "memory");
        __builtin_amdgcn_sched_barrier(0);

        // (b) convert to bf16 B-fragments
        bf16x8 xb[8];
#pragma unroll
        for (int kk = 0; kk < 8; ++kk) {
            union { unsigned u[4]; bf16x8 b; } p;
            p.u[0] = cvt_pk(v[2*kk][0],   v[2*kk][1]);
            p.u[1] = cvt_pk(v[2*kk][2],   v[2*kk][3]);
            p.u[2] = cvt_pk(v[2*kk+1][0], v[2*kk+1][1]);
            p.u[3] = cvt_pk(v[2*kk+1][2], v[2*kk+1][3]);
            xb[kk] = p.b;
        }

        // (c) issue next tile's x loads (stay in flight through all compute)
        if (t < 3) {
            const float* xr = x + ((size_t)(r0 + 16 + l15) * S_ + s) * IN_ + l4 * 8;
#pragma unroll
            for (int kk = 0; kk < 8; ++kk) {
                asm volatile("global_load_dwordx4 %0, %1, off" : "=v"(v[2*kk])   : "v"(xr + kk*32));
                asm volatile("global_load_dwordx4 %0, %1, off" : "=v"(v[2*kk+1]) : "v"(xr + kk*32 + 4));
            }
        }

        // (e) layer 1 swapped: D[h][m], acc[hf] covers h = hf*16 + l4*4+i, m = l15
        f32x4 acc[8];
#pragma unroll
        for (int hf = 0; hf < 8; ++hf)
#pragma unroll
            for (int i = 0; i < 4; ++i) acc[hf][i] = 0.0f;
#pragma unroll
        for (int kk = 0; kk < 8; ++kk) {
#pragma unroll
            for (int hf = 0; hf < 8; ++hf) {
                const int h = hf * 16 + l15;   // A-frag row
                const bf16x8 wf = *(const bf16x8*)(w1l + h * 512
                                   + ((kk * 64 + l4 * 16) ^ ((h & 7) << 4)));
                acc[hf] = __builtin_amdgcn_mfma_f32_16x16x32_bf16(wf, xb[kk], acc[hf], 0, 0, 0);
            }
        }

        // (f) bias + relu + pack -> private repack slice (swizzled)
#pragma unroll
        for (int hf = 0; hf < 8; ++hf) {
            const int h0 = hf * 16 + l4 * 4;
            unsigned p0 = cvt_pk(fmaxf(acc[hf][0] + b1v[hf].x, 0.f),
                                 fmaxf(acc[hf][1] + b1v[hf].y, 0.f));
            unsigned p1 = cvt_pk(fmaxf(acc[hf][2] + b1v[hf].z, 0.f),
                                 fmaxf(acc[hf][3] + b1v[hf].w, 0.f));
            ull p = (ull)p0 | ((ull)p1 << 32);
            *(ull*)(hsl + l15 * 256 + ((h0 * 2) ^ ((l15 & 7) << 4))) = p;
        }
        asm volatile("s_waitcnt lgkmcnt(0)" ::: "memory");   // same-wave LDS RAW
        __builtin_amdgcn_sched_barrier(0);

        // (h) read back as layer-2 A-fragments: lane l15 = m, 8 contiguous h
        bf16x8 pa[4];
#pragma unroll
        for (int kk = 0; kk < 4; ++kk)
            pa[kk] = *(const bf16x8*)(hsl + l15 * 256
                       + ((kk * 64 + l4 * 16) ^ ((l15 & 7) << 4)));

        // (i) layer 2 standard, two 128-col halves
#pragma unroll
        for (int oh = 0; oh < 2; ++oh) {
            f32x4 acc2[8];
#pragma unroll
            for (int of = 0; of < 8; ++of)
#pragma unroll
                for (int i = 0; i < 4; ++i) acc2[of][i] = 0.0f;
#pragma unroll
            for (int kk = 0; kk < 4; ++kk) {
#pragma unroll
                for (int of = 0; of < 8; ++of) {
                    const int o = oh * 128 + of * 16 + l15;   // B-frag col
                    const bf16x8 wf = *(const bf16x8*)(w2l + o * 256
                                       + ((kk * 64 + l4 * 16) ^ ((o & 7) << 4)));
                    acc2[of] = __builtin_amdgcn_mfma_f32_16x16x32_bf16(pa[kk], wf, acc2[of], 0, 0, 0);
                }
            }
#pragma unroll
            for (int of = 0; of < 8; ++of)
#pragma unroll
                for (int i = 0; i < 4; ++i) {
                    const int r = r0 + l4 * 4 + i;
                    out[((size_t)r * S_ + s) * OUT_ + oh * 128 + of * 16 + l15]
                        = acc2[of][i] + b2v[oh * 8 + of];
                }
        }
    }
}

extern "C" void kernel_launch(void* const* d_in, const int* in_sizes, int n_in,
                              void* d_out, int out_size, void* d_ws, size_t ws_size,
                              hipStream_t stream) {
    const float* x  = (const float*)d_in[0];
    const float* W1 = (const float*)d_in[1];
    const float* b1 = (const float*)d_in[2];
    const float* W2 = (const float*)d_in[3];
    const float* b2 = (const float*)d_in[4];
    float* out = (float*)d_out;

    unsigned short* w1t = (unsigned short*)d_ws;                 // [S][H][IN]  bf16: 2 MiB
    unsigned short* w2t = w1t + (size_t)S_ * H_ * IN_;           // [S][OUT][H] bf16: 2 MiB

    transpose_cvt_both<<<2048, 256, 0, stream>>>(W1, W2, w1t, w2t);
    subband_fused_kernel<<<256, 512, 0, stream>>>(x, w1t, b1, w2t, b2, out);
}

// Round 13
// 79.134 us; speedup vs baseline: 1.0998x; 1.0268x over previous
//
#include <hip/hip_runtime.h>
#include <hip/hip_bf16.h>

#define B_   4096
#define S_   32
#define IN_  256
#define H_   128
#define OUT_ 256

typedef __attribute__((ext_vector_type(8))) short bf16x8;
typedef __attribute__((ext_vector_type(4))) float f32x4;
typedef unsigned long long ull;

__device__ __forceinline__ unsigned short f2bf(float f) {
    union { float f; unsigned u; } v; v.f = f;
    unsigned r = v.u + 0x7FFFu + ((v.u >> 16) & 1u);   // RNE
    return (unsigned short)(r >> 16);
}
__device__ __forceinline__ unsigned cvt_pk(float lo, float hi) {
    unsigned r;
    asm("v_cvt_pk_bf16_f32 %0, %1, %2" : "=v"(r) : "v"(lo), "v"(hi));
    return r;
}

// pack_w1: W1 [S][IN(k)][H] f32 -> fragment-major bf16 A1 frags.
// w1f[s][kk=8][hf=8][lane=64][8]: lane: h-row = hf*16 + (l&15), k = kk*32 + (l>>4)*8 + j.
// Per-s block = 64KB contiguous (linear staging). grid = 32*8, block = 256.
__global__ __launch_bounds__(256) void pack_w1(const float* __restrict__ W1,
                                               unsigned short* __restrict__ w1f) {
    __shared__ float tile[32][129];                  // +1 pad: conflict-free emit reads
    const int bid = blockIdx.x, s = bid >> 3, kk = bid & 7;
    const int t = threadIdx.x;
#pragma unroll
    for (int i = 0; i < 16; ++i) {
        int idx = t + i * 256;                       // 32 k-rows x 128 h
        int kl = idx >> 7, h = idx & 127;
        tile[kl][h] = W1[((size_t)s * IN_ + kk * 32 + kl) * H_ + h];
    }
    __syncthreads();
#pragma unroll
    for (int rep = 0; rep < 2; ++rep) {
        int idx = t + rep * 256;                     // 8 hf x 64 lanes
        int hf = idx >> 6, l = idx & 63, l15 = l & 15, l4 = l >> 4;
        unsigned short o8[8];
#pragma unroll
        for (int j = 0; j < 8; ++j) o8[j] = f2bf(tile[l4 * 8 + j][hf * 16 + l15]);
        *(bf16x8*)(w1f + (((size_t)(s * 8 + kk) * 8 + hf) * 64 + l) * 8) = *(bf16x8*)o8;
    }
}

// pack_w2: W2 [S][H(k)][OUT] f32 -> fragment-major bf16 A2 frags (swapped L2).
// w2f[s][g=16][kkh=4][lane=64][8]: lane: o-row = g*16 + (l&15), h = kkh*32 + (l>>4)*8 + j.
// [g][kkh] order so g0..14 (60KB) stage linearly; g15 (4KB) goes to regs. grid = 32*4.
__global__ __launch_bounds__(256) void pack_w2(const float* __restrict__ W2,
                                               unsigned short* __restrict__ w2f) {
    __shared__ float tile[32][257];
    const int bid = blockIdx.x, s = bid >> 2, kkh = bid & 3;
    const int t = threadIdx.x;
#pragma unroll
    for (int i = 0; i < 32; ++i) {
        int idx = t + i * 256;                       // 32 h-rows x 256 o
        int kl = idx >> 8, o = idx & 255;
        tile[kl][o] = W2[((size_t)s * H_ + kkh * 32 + kl) * OUT_ + o];
    }
    __syncthreads();
#pragma unroll
    for (int rep = 0; rep < 4; ++rep) {
        int idx = t + rep * 256;                     // 16 g x 64 lanes
        int g = idx >> 6, l = idx & 63, l15 = l & 15, l4 = l >> 4;
        unsigned short o8[8];
#pragma unroll
        for (int j = 0; j < 8; ++j) o8[j] = f2bf(tile[l4 * 8 + j][g * 16 + l15]);
        *(bf16x8*)(w2f + (((size_t)(s * 16 + g) * 4 + kkh) * 64 + l) * 8) = *(bf16x8*)o8;
    }
}

// Weights-stationary fused MLP, fragment-major LDS (conflict-free weight reads).
// R10-proven sync discipline: tile-top vmcnt(0) with "+v" ties + normal stores.
// grid = 256 (1/CU), block = 512 (8 waves), ONE barrier. Wave: 4 tiles x 16 rows.
__global__ __launch_bounds__(512) void subband_fused_kernel(
        const float* __restrict__ x,
        const unsigned short* __restrict__ w1f,
        const unsigned short* __restrict__ w2f,
        const float* __restrict__ b1,
        const float* __restrict__ b2,
        float* __restrict__ out) {
    // LDS map: [0,64K) w1l | [64K,124K) w2l g0..14 | [124K,+32K) rep 8x4KB
    //          | b1l 512B | b2l 1KB  => 161280 B total
    __shared__ __align__(16) unsigned char lds[161280];
    unsigned char* w1l = lds;
    unsigned char* w2l = lds + 65536;
    unsigned char* repb = lds + 126976;
    float* b1l = (float*)(lds + 159744);
    float* b2l = (float*)(lds + 160256);

    const int bid = blockIdx.x;                // consecutive s-blocks share XCD L2
    const int s   = bid & 31;
    const int chunk = bid >> 5;                // rows [chunk*512, +512)
    const int tid = threadIdx.x;
    const int w = tid >> 6, l = tid & 63, l15 = l & 15, l4 = l >> 4;
    unsigned char* rep = repb + w * 4096;
    const int rw = chunk * 512 + w * 64;       // wave's 64 rows

#define LDG(dst, p) asm volatile("global_load_dwordx4 %0, %1, off" : "=v"(dst) : "v"(p))

    // ---- issue tile-0 x loads first (HBM latency overlaps weight staging) ----
    f32x4 v[16];
    {
        const float* xr = x + ((size_t)(rw + l15) * S_ + s) * IN_ + l4 * 8;
#pragma unroll
        for (int kk = 0; kk < 8; ++kk) {
            LDG(v[2 * kk],     xr + kk * 32);
            LDG(v[2 * kk + 1], xr + kk * 32 + 4);
        }
    }

    // ---- stage weights: linear coalesced copies (fragment-major already) ----
    const unsigned char* w1src = (const unsigned char*)(w1f + (size_t)s * 32768);
#pragma unroll
    for (int i = 0; i < 8; ++i)
        *(bf16x8*)(w1l + tid * 16 + i * 8192) = *(const bf16x8*)(w1src + tid * 16 + i * 8192);
    const unsigned char* w2src = (const unsigned char*)(w2f + (size_t)s * 32768);
#pragma unroll
    for (int i = 0; i < 7; ++i)
        *(bf16x8*)(w2l + tid * 16 + i * 8192) = *(const bf16x8*)(w2src + tid * 16 + i * 8192);
    if (tid < 256)
        *(bf16x8*)(w2l + tid * 16 + 57344) = *(const bf16x8*)(w2src + tid * 16 + 57344);

    // g15 W2 fragments -> registers (reused across all 4 tiles)
    bf16x8 w2r[4];
#pragma unroll
    for (int kkh = 0; kkh < 4; ++kkh)
        w2r[kkh] = *(const bf16x8*)(w2src + (((size_t)15 * 4 + kkh) * 64 + l) * 16);

    // biases -> LDS (float4-broadcast reads later)
    if (tid < 128)      b1l[tid]       = b1[s * H_ + tid];
    else if (tid < 384) b2l[tid - 128] = b2[s * OUT_ + (tid - 128)];

    __syncthreads();                           // the ONLY barrier

    float* opbase = out + ((size_t)(rw + l15) * S_ + s) * OUT_;

#pragma unroll 1
    for (int t = 0; t < 4; ++t) {
        // ---- tile-top wait: drain everything (R10-proven; immune to FIFO miscount) ----
        asm volatile("s_waitcnt vmcnt(0)"
            : "+v"(v[0]), "+v"(v[1]), "+v"(v[2]), "+v"(v[3]),
              "+v"(v[4]), "+v"(v[5]), "+v"(v[6]), "+v"(v[7]),
              "+v"(v[8]), "+v"(v[9]), "+v"(v[10]), "+v"(v[11]),
              "+v"(v[12]), "+v"(v[13]), "+v"(v[14]), "+v"(v[15]) :: "memory");
        __builtin_amdgcn_sched_barrier(0);

        // ---- convert to B-fragments: lane m = l15, k = kk*32 + l4*8 + j ----
        bf16x8 xb[8];
#pragma unroll
        for (int kk = 0; kk < 8; ++kk) {
            union { unsigned u[4]; bf16x8 b; } p;
            p.u[0] = cvt_pk(v[2 * kk][0],     v[2 * kk][1]);
            p.u[1] = cvt_pk(v[2 * kk][2],     v[2 * kk][3]);
            p.u[2] = cvt_pk(v[2 * kk + 1][0], v[2 * kk + 1][1]);
            p.u[3] = cvt_pk(v[2 * kk + 1][2], v[2 * kk + 1][3]);
            xb[kk] = p.b;
        }

        // ---- issue next tile's x loads (in flight through all compute) ----
        if (t < 3) {
            const float* xr = x + ((size_t)(rw + (t + 1) * 16 + l15) * S_ + s) * IN_ + l4 * 8;
#pragma unroll
            for (int kk = 0; kk < 8; ++kk) {
                LDG(v[2 * kk],     xr + kk * 32);
                LDG(v[2 * kk + 1], xr + kk * 32 + 4);
            }
        }

        // ---- layer 1 swapped: acc1[hf] holds h = hf*16 + l4*4 + i, m = l15 ----
        f32x4 acc1[8];
#pragma unroll
        for (int hf = 0; hf < 8; ++hf) {
            const float4 bv = *(const float4*)(b1l + hf * 16 + l4 * 4);
            acc1[hf][0] = bv.x; acc1[hf][1] = bv.y; acc1[hf][2] = bv.z; acc1[hf][3] = bv.w;
        }
#pragma unroll
        for (int kk = 0; kk < 8; ++kk)
#pragma unroll
            for (int hf = 0; hf < 8; ++hf) {
                const bf16x8 wf = *(const bf16x8*)(w1l + ((kk * 8 + hf) * 64 + l) * 16);
                acc1[hf] = __builtin_amdgcn_mfma_f32_16x16x32_bf16(wf, xb[kk], acc1[hf], 0, 0, 0);
            }

        // ---- relu + repack -> fragment-major rep (mapping hand-verified) ----
#pragma unroll
        for (int hf = 0; hf < 8; ++hf) {
            unsigned p0 = cvt_pk(fmaxf(acc1[hf][0], 0.f), fmaxf(acc1[hf][1], 0.f));
            unsigned p1 = cvt_pk(fmaxf(acc1[hf][2], 0.f), fmaxf(acc1[hf][3], 0.f));
            ull p = (ull)p0 | ((ull)p1 << 32);
            const int kkh = hf >> 1;
            const int l4p = ((hf & 1) << 1) | (l4 >> 1);
            *(ull*)(rep + kkh * 1024 + (l4p * 16 + l15) * 16 + ((l4 & 1) * 8)) = p;
        }
        asm volatile("s_waitcnt lgkmcnt(0)" ::: "memory");     // same-wave LDS RAW
        __builtin_amdgcn_sched_barrier(0);

        // h fragments: lane m = l15, k-h = kkh*32 + l4*8 + j (contiguous 1KB reads)
        bf16x8 hfr[4];
#pragma unroll
        for (int kkh = 0; kkh < 4; ++kkh)
            hfr[kkh] = *(const bf16x8*)(rep + kkh * 1024 + l * 16);

        // ---- layer 2 swapped: D2[o][m]; o = g*16 + l4*4 + i, m = l15 ----
        float* op = opbase + (size_t)t * 16 * S_ * OUT_;
#pragma unroll
        for (int g = 0; g < 16; ++g) {
            const float4 bv = *(const float4*)(b2l + g * 16 + l4 * 4);
            f32x4 acc2;
            acc2[0] = bv.x; acc2[1] = bv.y; acc2[2] = bv.z; acc2[3] = bv.w;
#pragma unroll
            for (int kkh = 0; kkh < 4; ++kkh) {
                const bf16x8 wf = (g < 15)
                    ? *(const bf16x8*)(w2l + ((g * 4 + kkh) * 64 + l) * 16)
                    : w2r[kkh];
                acc2 = __builtin_amdgcn_mfma_f32_16x16x32_bf16(wf, hfr[kkh], acc2, 0, 0, 0);
            }
            *(f32x4*)(op + g * 16 + l4 * 4) = acc2;   // normal store, 16B/lane
        }
    }
#undef LDG
}

extern "C" void kernel_launch(void* const* d_in, const int* in_sizes, int n_in,
                              void* d_out, int out_size, void* d_ws, size_t ws_size,
                              hipStream_t stream) {
    const float* x  = (const float*)d_in[0];
    const float* W1 = (const float*)d_in[1];
    const float* b1 = (const float*)d_in[2];
    const float* W2 = (const float*)d_in[3];
    const float* b2 = (const float*)d_in[4];
    float* out = (float*)d_out;

    unsigned short* w1f = (unsigned short*)d_ws;                 // 2 MiB
    unsigned short* w2f = w1f + (size_t)S_ * 8 * 8 * 64 * 8;     // 2 MiB (total = 4 MiB)

    pack_w1<<<S_ * 8, 256, 0, stream>>>(W1, w1f);
    pack_w2<<<S_ * 4, 256, 0, stream>>>(W2, w2f);
    subband_fused_kernel<<<256, 512, 0, stream>>>(x, w1f, w2f, b1, b2, out);
}